// Round 4
// baseline (286.967 us; speedup 1.0000x reference)
//
#include <hip/hip_runtime.h>
#include <cstddef>

// CAM module, algebraically restructured:
//   X = concat(rgb,hsv,lab) : [B=4, 192, N=65536] (f32)
//   G[b] = X X^T (192x192), s[b] = row sums        (K1, fp16 MFMA, 2 blocks/CU, LDS dbuf)
//   energy = (Wq G Wk^T + bq sk^T + sq bk^T + N bq bk^T)/8 ; att = softmax_d
//   M = att Wv (emitted as swizzled fp16) ; c0 = att bv   (K2, f32)
//   out = M X + c0                                  (K3, fp16 MFMA, memory-bound)

#define NPIX 65536

typedef _Float16 half4_t __attribute__((ext_vector_type(4)));
typedef _Float16 half8_t __attribute__((ext_vector_type(8)));
typedef float f32x4_t __attribute__((ext_vector_type(4)));

// ---------------- K0: zero a float range ----------------
__global__ void k0_zero(float* __restrict__ p, int n) {
  int i = blockIdx.x * 256 + threadIdx.x;
  if (i < n) p[i] = 0.0f;
}

// ---------------- K1: Gram + row sums ----------------
// grid (128, 4) = 512 blocks (2/CU), block 768 (12 waves as 3 row-groups x 4 col-groups).
// 512 cols/block, 8 chunks of 64 cols, LDS double-buffered (1 barrier/chunk),
// loads issued after the barrier (no vmcnt drain of in-flight prefetch).
// mode: 2 = direct partials (128 slots/batch), 1 = atomicAdd partials (64 slots/batch,
// part pre-zeroed), 0 = atomicAdd into zeroed G (last resort).
__global__ __launch_bounds__(768, 6) void k1_gram(
    const float* __restrict__ rgb, const float* __restrict__ hsv, const float* __restrict__ lab,
    float* __restrict__ G, float* __restrict__ S, float* __restrict__ part, int mode) {
  __shared__ alignas(16) _Float16 lds2[2][12288];
  float* slds = (float*)&lds2[0][0];

  const int t = threadIdx.x;
  const int lane = t & 63;
  const int w = t >> 6;          // 0..11
  const int wi = w >> 2;         // 0..2: row group (4 tiles = 64 rows)
  const int wj = w & 3;          // 0..3: col group (3 tiles = 48 cols)
  const int b = blockIdx.y;
  const int bx = blockIdx.x;     // 0..127
  const int n0 = bx * 512;

  const int row = t >> 2;        // 0..191
  const int cq = (t & 3) << 4;   // 0,16,32,48
  const float* srcs[3] = {rgb, hsv, lab};
  const float* gp = srcs[row >> 6] + (size_t)(b * 64 + (row & 63)) * NPIX + n0 + cq;

  f32x4_t acc[4][3];
  const f32x4_t zero4 = {0.0f, 0.0f, 0.0f, 0.0f};
#pragma unroll
  for (int a = 0; a < 4; ++a)
#pragma unroll
    for (int j = 0; j < 3; ++j) acc[a][j] = zero4;
  float s_acc = 0.0f;

  const int sw = (row & 7) << 3;   // swizzle (fp16 units)
  const int rbase = row * 64;

  float4 R0, R1, R2, R3;
  auto loadR = [&](int cc) {
    const float* p = gp + cc * 64;
    R0 = *(const float4*)(p + 0); R1 = *(const float4*)(p + 4);
    R2 = *(const float4*)(p + 8); R3 = *(const float4*)(p + 12);
  };
  auto writeL = [&](_Float16* buf) {
    s_acc += (R0.x + R0.y + R0.z + R0.w) + (R1.x + R1.y + R1.z + R1.w) +
             (R2.x + R2.y + R2.z + R2.w) + (R3.x + R3.y + R3.z + R3.w);
    half4_t h;
    h.x = (_Float16)R0.x; h.y = (_Float16)R0.y; h.z = (_Float16)R0.z; h.w = (_Float16)R0.w;
    *(half4_t*)(buf + rbase + ((cq + 0) ^ sw)) = h;
    h.x = (_Float16)R1.x; h.y = (_Float16)R1.y; h.z = (_Float16)R1.z; h.w = (_Float16)R1.w;
    *(half4_t*)(buf + rbase + ((cq + 4) ^ sw)) = h;
    h.x = (_Float16)R2.x; h.y = (_Float16)R2.y; h.z = (_Float16)R2.z; h.w = (_Float16)R2.w;
    *(half4_t*)(buf + rbase + ((cq + 8) ^ sw)) = h;
    h.x = (_Float16)R3.x; h.y = (_Float16)R3.y; h.z = (_Float16)R3.z; h.w = (_Float16)R3.w;
    *(half4_t*)(buf + rbase + ((cq + 12) ^ sw)) = h;
  };
  auto compute = [&](const _Float16* buf) {
#pragma unroll
    for (int ks = 0; ks < 2; ++ks) {
      const int kc = ks * 32 + 8 * (lane >> 4);
      half8_t fA[4], fB[3];
#pragma unroll
      for (int a = 0; a < 4; ++a) {
        int rA = wi * 64 + a * 16 + (lane & 15);
        fA[a] = *(const half8_t*)(buf + rA * 64 + (kc ^ ((rA & 7) << 3)));
      }
#pragma unroll
      for (int j = 0; j < 3; ++j) {
        int rB = wj * 48 + j * 16 + (lane & 15);
        fB[j] = *(const half8_t*)(buf + rB * 64 + (kc ^ ((rB & 7) << 3)));
      }
#pragma unroll
      for (int a = 0; a < 4; ++a)
#pragma unroll
        for (int j = 0; j < 3; ++j)
          acc[a][j] = __builtin_amdgcn_mfma_f32_16x16x32_f16(fA[a], fB[j], acc[a][j], 0, 0, 0);
    }
  };

  loadR(0);
  for (int cc = 0; cc < 8; ++cc) {
    writeL(&lds2[cc & 1][0]);   // waits on loads issued one compute-phase ago
    __syncthreads();            // buf[cc&1] staged; prior reads of it long done
    if (cc + 1 < 8) loadR(cc + 1);  // issue AFTER barrier: never drained by it
    compute(&lds2[cc & 1][0]);
  }
  __syncthreads();

  // ---- flush Gram ----
  if (mode == 2) {
    float* pb = part + (size_t)(b * 128 + bx) * 37056;
#pragma unroll
    for (int a = 0; a < 4; ++a)
#pragma unroll
      for (int j = 0; j < 3; ++j) {
        int tt = (wi * 4 + a) * 12 + (wj * 3 + j);
        *(f32x4_t*)(pb + tt * 256 + lane * 4) = acc[a][j];
      }
  } else if (mode == 1) {
    float* pb = part + (size_t)(b * 64 + (bx >> 1)) * 37056;
#pragma unroll
    for (int a = 0; a < 4; ++a)
#pragma unroll
      for (int j = 0; j < 3; ++j) {
        int tt = (wi * 4 + a) * 12 + (wj * 3 + j);
#pragma unroll
        for (int r = 0; r < 4; ++r)
          atomicAdd(pb + tt * 256 + lane * 4 + r, acc[a][j][r]);
      }
  } else {
    float* Gb = G + b * 36864;
#pragma unroll
    for (int a = 0; a < 4; ++a)
#pragma unroll
      for (int j = 0; j < 3; ++j) {
        int I = wi * 4 + a, J = wj * 3 + j;
#pragma unroll
        for (int r = 0; r < 4; ++r) {
          int gr = I * 16 + ((lane >> 4) << 2) + r;
          int gc = J * 16 + (lane & 15);
          atomicAdd(Gb + gr * 192 + gc, acc[a][j][r]);
        }
      }
  }

  // ---- row sums (reuse first LDS buffer as f32; disjoint from last compute buf) ----
  slds[t] = s_acc;
  __syncthreads();
  if (t < 192) {
    float s = (slds[t * 4] + slds[t * 4 + 1]) + (slds[t * 4 + 2] + slds[t * 4 + 3]);
    if (mode == 2)
      part[(size_t)(b * 128 + bx) * 37056 + 36864 + t] = s;
    else if (mode == 1)
      atomicAdd(part + (size_t)(b * 64 + (bx >> 1)) * 37056 + 36864 + t, s);
    else
      atomicAdd(S + b * 192 + t, s);
  }
}

// ---------------- K1.5: deterministic reduce of P partials/batch ----------------
__global__ void k1r_reduce(const float* __restrict__ part, float* __restrict__ G,
                           float* __restrict__ S, int P) {
  int idx = blockIdx.x * 256 + threadIdx.x;
  if (idx >= 4 * 37056) return;
  int b = idx / 37056;
  int flat = idx % 37056;
  const float* base = part + (size_t)b * P * 37056 + flat;
  float v0 = 0.f, v1 = 0.f, v2 = 0.f, v3 = 0.f;
  for (int q = 0; q < P; q += 4) {
    v0 += base[(size_t)(q + 0) * 37056];
    v1 += base[(size_t)(q + 1) * 37056];
    v2 += base[(size_t)(q + 2) * 37056];
    v3 += base[(size_t)(q + 3) * 37056];
  }
  float v = (v0 + v1) + (v2 + v3);
  if (flat < 36864) {
    int tt = flat >> 8;
    int I = tt / 12, J = tt % 12;
    int r = flat & 255;
    int lane = r >> 2, rg = r & 3;
    int row = I * 16 + ((lane >> 4) << 2) + rg;
    int col = J * 16 + (lane & 15);
    G[b * 36864 + row * 192 + col] = v;
  } else {
    S[b * 192 + (flat - 36864)] = v;
  }
}

// ---------------- K2: energy -> softmax -> M(fp16 swizzled), c0 ----------------
__global__ __launch_bounds__(256) void k2_small(
    const float* __restrict__ G, const float* __restrict__ S,
    const float* __restrict__ Wq, const float* __restrict__ bq,
    const float* __restrict__ Wk, const float* __restrict__ bk,
    const float* __restrict__ Wv, const float* __restrict__ bv,
    _Float16* __restrict__ Mh, float* __restrict__ c0w) {
  const int b = blockIdx.y;
  const int cbase = blockIdx.x * 8;
  const int t = threadIdx.x;
  __shared__ float T1[192 * 9];
  __shared__ float el[64 * 8];
  __shared__ float sq[8];
  __shared__ float sk[64];
  const float* Gb = G + b * 36864;
  const float* Sb = S + b * 192;

  if (t < 8) {
    float a = 0.f;
    const float* wq = Wq + (cbase + t) * 192;
    for (int i = 0; i < 192; ++i) a = fmaf(wq[i], Sb[i], a);
    sq[t] = a;
  } else if (t < 72) {
    int d = t - 8;
    float a = 0.f;
    const float* wk = Wk + d * 192;
    for (int j = 0; j < 192; ++j) a = fmaf(wk[j], Sb[j], a);
    sk[d] = a;
  }
  for (int e = t; e < 1536; e += 256) {
    int j = e % 192, cp = e / 192;
    const float* wq = Wq + (cbase + cp) * 192;
    float a = 0.f;
    for (int i = 0; i < 192; ++i) a = fmaf(wq[i], Gb[i * 192 + j], a);
    T1[j * 9 + cp] = a;
  }
  __syncthreads();
  for (int e = t; e < 512; e += 256) {
    int cp = e & 7, d = e >> 3;
    const float* wk = Wk + d * 192;
    float a = 0.f;
    for (int j = 0; j < 192; ++j) a = fmaf(T1[j * 9 + cp], wk[j], a);
    float bqc = bq[cbase + cp], bkd = bk[d];
    a += bqc * sk[d] + bkd * sq[cp] + 65536.0f * bqc * bkd;
    el[d * 8 + cp] = a * 0.125f;
  }
  __syncthreads();
  if (t < 8) {
    float mx = -3.0e38f;
    for (int d = 0; d < 64; ++d) mx = fmaxf(mx, el[d * 8 + t]);
    float sum = 0.f;
    for (int d = 0; d < 64; ++d) {
      float pv = expf(el[d * 8 + t] - mx);
      el[d * 8 + t] = pv;
      sum += pv;
    }
    float inv = 1.0f / sum;
    for (int d = 0; d < 64; ++d) el[d * 8 + t] *= inv;
  }
  __syncthreads();
  // M rows in fp16, swizzled exactly as K3's lds_m image: idx = c*192 + (i ^ ((c&7)<<3))
  for (int e = t; e < 1536; e += 256) {
    int i = e % 192, cp = e / 192;
    int c = cbase + cp;
    float a = 0.f;
    for (int d = 0; d < 64; ++d) a = fmaf(el[d * 8 + cp], Wv[d * 192 + i], a);
    Mh[(size_t)b * 12288 + c * 192 + (i ^ ((c & 7) << 3))] = (_Float16)a;
  }
  if (t < 8) {
    float a = 0.f;
    for (int d = 0; d < 64; ++d) a = fmaf(el[d * 8 + t], bv[d], a);
    c0w[b * 64 + cbase + t] = a;
  }
}

// ---------------- K3: out = M X + c0 (fp16 MFMA) ----------------
// grid (256, 4), block 256 (4 waves). Block: C[64 x 256n]; wave w: n-span w*64.
// X chunk [32 i][256 n] staged transposed into lds_x[n][32] fp16, swizzle i^=(n&3)<<3.
// M staged once (linear copy of pre-swizzled fp16 image). acc[4][4] = 64 VGPR.
__global__ __launch_bounds__(256, 3) void k3_out(
    const float* __restrict__ rgb, const float* __restrict__ hsv, const float* __restrict__ lab,
    const _Float16* __restrict__ Mh, const float* __restrict__ c0w, float* __restrict__ out) {
  __shared__ alignas(16) _Float16 lds_m[12288];
  __shared__ alignas(16) _Float16 lds_x[8192];
  __shared__ float c0l[64];
  const int t = threadIdx.x;
  const int lane = t & 63;
  const int w = t >> 6;
  const int b = blockIdx.y;
  const int nblk = blockIdx.x * 256;

  {  // stage M (24576 B) as 16B copies + c0
    const float4* msrc = (const float4*)(Mh + (size_t)b * 12288);
    float4* mdst = (float4*)lds_m;
#pragma unroll
    for (int k = 0; k < 6; ++k) mdst[t + 256 * k] = msrc[t + 256 * k];
    if (t < 64) c0l[t] = c0w[b * 64 + t];
  }

  const int xi = t & 31;   // i within chunk
  const int ng = t >> 5;   // 0..7: n-group of 32
  const float* srcs[3] = {rgb, hsv, lab};

  f32x4_t acc[4][4];
  const f32x4_t zero4 = {0.0f, 0.0f, 0.0f, 0.0f};
#pragma unroll
  for (int i = 0; i < 4; ++i)
#pragma unroll
    for (int j = 0; j < 4; ++j) acc[i][j] = zero4;

  float4 xr[8];
  auto xload = [&](int kc) {
    int ig = kc * 32 + xi;
    const float* p = srcs[ig >> 6] + (size_t)(b * 64 + (ig & 63)) * NPIX + nblk + ng * 32;
#pragma unroll
    for (int f = 0; f < 8; ++f) xr[f] = *(const float4*)(p + f * 4);
  };
  auto xwrite = [&]() {
#pragma unroll
    for (int f = 0; f < 8; ++f) {
      int n = ng * 32 + f * 4;
      lds_x[(n + 0) * 32 + (xi ^ 0)]  = (_Float16)xr[f].x;
      lds_x[(n + 1) * 32 + (xi ^ 8)]  = (_Float16)xr[f].y;
      lds_x[(n + 2) * 32 + (xi ^ 16)] = (_Float16)xr[f].z;
      lds_x[(n + 3) * 32 + (xi ^ 24)] = (_Float16)xr[f].w;
    }
  };

  const int g = lane >> 4;     // 0..3
  const int l15 = lane & 15;

  xload(0);
  for (int kc = 0; kc < 6; ++kc) {
    xwrite();
    __syncthreads();
    if (kc + 1 < 6) xload(kc + 1);
    half8_t fx[4], fm[4];
#pragma unroll
    for (int nt = 0; nt < 4; ++nt) {
      int n = w * 64 + nt * 16 + l15;
      fx[nt] = *(const half8_t*)(lds_x + n * 32 + ((8 * g) ^ ((n & 3) << 3)));
    }
#pragma unroll
    for (int ct = 0; ct < 4; ++ct) {
      int c = ct * 16 + l15;
      fm[ct] = *(const half8_t*)(lds_m + c * 192 + ((kc * 32 + 8 * g) ^ ((c & 7) << 3)));
    }
#pragma unroll
    for (int nt = 0; nt < 4; ++nt)
#pragma unroll
      for (int ct = 0; ct < 4; ++ct)
        acc[nt][ct] = __builtin_amdgcn_mfma_f32_16x16x32_f16(fx[nt], fm[ct], acc[nt][ct], 0, 0, 0);
    __syncthreads();
  }

  // epilogue: C-row (n) = 4*g + r from first operand, C-col (c) = l15 from second
#pragma unroll
  for (int ct = 0; ct < 4; ++ct) {
    int c = ct * 16 + l15;
    float c0v = c0l[c];
#pragma unroll
    for (int nt = 0; nt < 4; ++nt) {
      int n = nblk + w * 64 + nt * 16 + 4 * g;
      float4 o;
      o.x = acc[nt][ct][0] + c0v;
      o.y = acc[nt][ct][1] + c0v;
      o.z = acc[nt][ct][2] + c0v;
      o.w = acc[nt][ct][3] + c0v;
      *(float4*)(out + (size_t)(b * 64 + c) * NPIX + n) = o;
    }
  }
}

extern "C" void kernel_launch(void* const* d_in, const int* in_sizes, int n_in,
                              void* d_out, int out_size, void* d_ws, size_t ws_size,
                              hipStream_t stream) {
  const float* rgb = (const float*)d_in[0];
  const float* hsv = (const float*)d_in[1];
  const float* lab = (const float*)d_in[2];
  const float* Wq = (const float*)d_in[3];
  const float* bq = (const float*)d_in[4];
  const float* Wk = (const float*)d_in[5];
  const float* bk = (const float*)d_in[6];
  const float* Wv = (const float*)d_in[7];
  const float* bv = (const float*)d_in[8];
  float* out = (float*)d_out;
  float* ws = (float*)d_ws;

  float* G = ws;                            // 147456 f32
  float* S = ws + 147456;                   // 768
  _Float16* Mh = (_Float16*)(ws + 148224);  // 49152 halves = 24576 f32 slots
  float* c0w = ws + 172800;                 // 256
  float* part = ws + 173056;                // up to 512*37056 f32
  const size_t need2 = (size_t)(173056 + 512 * 37056) * 4;  // 76.6 MB
  const size_t need1 = (size_t)(173056 + 256 * 37056) * 4;  // 38.6 MB
  const int mode = ws_size >= need2 ? 2 : (ws_size >= need1 ? 1 : 0);

  if (mode == 1)
    k0_zero<<<dim3(37056), dim3(256), 0, stream>>>(part, 256 * 37056);
  else if (mode == 0)
    k0_zero<<<dim3(579), dim3(256), 0, stream>>>(ws, 148224);  // zero G + S

  k1_gram<<<dim3(128, 4), dim3(768), 0, stream>>>(rgb, hsv, lab, G, S, part, mode);
  if (mode)
    k1r_reduce<<<dim3(579), dim3(256), 0, stream>>>(part, G, S, mode == 2 ? 128 : 64);
  k2_small<<<dim3(8, 4), dim3(256), 0, stream>>>(G, S, Wq, bq, Wk, bk, Wv, bv, Mh, c0w);
  k3_out<<<dim3(256, 4), dim3(256), 0, stream>>>(rgb, hsv, lab, Mh, c0w, out);
}

// Round 5
// 167.505 us; speedup vs baseline: 1.7132x; 1.7132x over previous
//
#include <hip/hip_runtime.h>
#include <cstddef>

// CAM module, algebraically restructured:
//   X = concat(rgb,hsv,lab) : [B=4, 192, N=65536] (f32)
//   G[b] = X X^T (192x192), s[b] = row sums        (K1, fp16 MFMA)
//   energy = (Wq G Wk^T + bq sk^T + sq bk^T + N bq bk^T)/8 ; att = softmax_d
//   M = att Wv (emitted as swizzled fp16) ; c0 = att bv   (K2, f32)
//   out = M X + c0                                  (K3, fp16 MFMA, memory-bound)
//
// Round-4 lesson: do NOT force min-waves in __launch_bounds__ on the register-
// heavy K1 (spilled to scratch: 40 VGPR + 460 MB spill traffic). Round-3 K1
// compiles to 80 VGPR naturally, which already fits 2 blocks/CU; it was only
// grid-limited (256 blocks). This round: same kernel, grid 512 blocks.

#define NPIX 65536

typedef _Float16 half4_t __attribute__((ext_vector_type(4)));
typedef _Float16 half8_t __attribute__((ext_vector_type(8)));
typedef float f32x4_t __attribute__((ext_vector_type(4)));

// ---------------- K0: zero a float range ----------------
__global__ void k0_zero(float* __restrict__ p, int n) {
  int i = blockIdx.x * 256 + threadIdx.x;
  if (i < n) p[i] = 0.0f;
}

// ---------------- K1: Gram + row sums ----------------
// grid (128, 4) = 512 blocks -> 2 blocks/CU co-resident, block 768 (12 waves, 2x6).
// 512 cols/block, 8 chunks of 64 cols, single LDS buffer, 2 barriers/chunk,
// 2-deep register prefetch (A=chunk c, B=c+1; load c+2 during compute of c).
// mode: 2 = direct partials (128/batch), 1 = atomic partials (64/batch, pre-zeroed),
// 0 = atomicAdd into zeroed G.
__global__ __launch_bounds__(768, 3) void k1_gram(
    const float* __restrict__ rgb, const float* __restrict__ hsv, const float* __restrict__ lab,
    float* __restrict__ G, float* __restrict__ S, float* __restrict__ part, int mode) {
  __shared__ alignas(16) unsigned char smem[24576];
  _Float16* lds = (_Float16*)smem;
  float* slds = (float*)smem;

  const int t = threadIdx.x;
  const int lane = t & 63;
  const int w = t >> 6;          // 0..11
  const int wi = w & 1;          // 0..1: row group (6 tiles = 96 rows)
  const int wj = w >> 1;         // 0..5: col group (2 tiles = 32 cols)
  const int b = blockIdx.y;
  const int bx = blockIdx.x;     // 0..127
  const int n0 = bx * 512;

  const int row = t >> 2;        // 0..191
  const int cq = (t & 3) << 4;   // 0,16,32,48
  const float* srcs[3] = {rgb, hsv, lab};
  const float* gp = srcs[row >> 6] + (size_t)(b * 64 + (row & 63)) * NPIX + n0 + cq;

  f32x4_t acc[6][2];
  const f32x4_t zero4 = {0.0f, 0.0f, 0.0f, 0.0f};
#pragma unroll
  for (int a = 0; a < 6; ++a)
#pragma unroll
    for (int j = 0; j < 2; ++j) acc[a][j] = zero4;
  float s_acc = 0.0f;

  const int sw = (row & 7) << 3;   // swizzle (fp16 units)
  const int rbase = row * 64;

  float4 A0, A1, A2, A3, B0, B1, B2, B3;
  auto loadA = [&](int cc) {
    const float* p = gp + cc * 64;
    A0 = *(const float4*)(p + 0); A1 = *(const float4*)(p + 4);
    A2 = *(const float4*)(p + 8); A3 = *(const float4*)(p + 12);
  };
  auto loadB = [&](int cc) {
    const float* p = gp + cc * 64;
    B0 = *(const float4*)(p + 0); B1 = *(const float4*)(p + 4);
    B2 = *(const float4*)(p + 8); B3 = *(const float4*)(p + 12);
  };
  auto writeLDS = [&](float4 r0, float4 r1, float4 r2, float4 r3) {
    s_acc += (r0.x + r0.y + r0.z + r0.w) + (r1.x + r1.y + r1.z + r1.w) +
             (r2.x + r2.y + r2.z + r2.w) + (r3.x + r3.y + r3.z + r3.w);
    half4_t h;
    h.x = (_Float16)r0.x; h.y = (_Float16)r0.y; h.z = (_Float16)r0.z; h.w = (_Float16)r0.w;
    *(half4_t*)(lds + rbase + ((cq + 0) ^ sw)) = h;
    h.x = (_Float16)r1.x; h.y = (_Float16)r1.y; h.z = (_Float16)r1.z; h.w = (_Float16)r1.w;
    *(half4_t*)(lds + rbase + ((cq + 4) ^ sw)) = h;
    h.x = (_Float16)r2.x; h.y = (_Float16)r2.y; h.z = (_Float16)r2.z; h.w = (_Float16)r2.w;
    *(half4_t*)(lds + rbase + ((cq + 8) ^ sw)) = h;
    h.x = (_Float16)r3.x; h.y = (_Float16)r3.y; h.z = (_Float16)r3.z; h.w = (_Float16)r3.w;
    *(half4_t*)(lds + rbase + ((cq + 12) ^ sw)) = h;
  };
  auto compute = [&]() {
#pragma unroll
    for (int ks = 0; ks < 2; ++ks) {
      const int kc = ks * 32 + 8 * (lane >> 4);
      half8_t fA[6], fB[2];
#pragma unroll
      for (int a = 0; a < 6; ++a) {
        int rA = wi * 96 + a * 16 + (lane & 15);
        fA[a] = *(const half8_t*)(lds + rA * 64 + (kc ^ ((rA & 7) << 3)));
      }
#pragma unroll
      for (int j = 0; j < 2; ++j) {
        int rB = (wj * 2 + j) * 16 + (lane & 15);
        fB[j] = *(const half8_t*)(lds + rB * 64 + (kc ^ ((rB & 7) << 3)));
      }
#pragma unroll
      for (int a = 0; a < 6; ++a)
#pragma unroll
        for (int j = 0; j < 2; ++j)
          acc[a][j] = __builtin_amdgcn_mfma_f32_16x16x32_f16(fA[a], fB[j], acc[a][j], 0, 0, 0);
    }
  };

  loadA(0);
  loadB(1);
  for (int cc = 0; cc < 8; cc += 2) {
    writeLDS(A0, A1, A2, A3);
    __syncthreads();
    if (cc + 2 < 8) loadA(cc + 2);
    compute();
    __syncthreads();
    writeLDS(B0, B1, B2, B3);
    __syncthreads();
    if (cc + 3 < 8) loadB(cc + 3);
    compute();
    __syncthreads();
  }

  // ---- flush Gram ----
  if (mode == 2) {
    float* pb = part + (size_t)(b * 128 + bx) * 37056;
#pragma unroll
    for (int a = 0; a < 6; ++a)
#pragma unroll
      for (int j = 0; j < 2; ++j) {
        int tt = (wi * 6 + a) * 12 + (wj * 2 + j);
        *(f32x4_t*)(pb + tt * 256 + lane * 4) = acc[a][j];
      }
  } else if (mode == 1) {
    float* pb = part + (size_t)(b * 64 + (bx >> 1)) * 37056;
#pragma unroll
    for (int a = 0; a < 6; ++a)
#pragma unroll
      for (int j = 0; j < 2; ++j) {
        int tt = (wi * 6 + a) * 12 + (wj * 2 + j);
#pragma unroll
        for (int r = 0; r < 4; ++r)
          atomicAdd(pb + tt * 256 + lane * 4 + r, acc[a][j][r]);
      }
  } else {
    float* Gb = G + b * 36864;
#pragma unroll
    for (int a = 0; a < 6; ++a)
#pragma unroll
      for (int j = 0; j < 2; ++j) {
        int I = wi * 6 + a, J = wj * 2 + j;
#pragma unroll
        for (int r = 0; r < 4; ++r) {
          int gr = I * 16 + ((lane >> 4) << 2) + r;
          int gc = J * 16 + (lane & 15);
          atomicAdd(Gb + gr * 192 + gc, acc[a][j][r]);
        }
      }
  }

  // ---- row sums (reuse LDS as f32) ----
  slds[t] = s_acc;
  __syncthreads();
  if (t < 192) {
    float s = (slds[t * 4] + slds[t * 4 + 1]) + (slds[t * 4 + 2] + slds[t * 4 + 3]);
    if (mode == 2)
      part[(size_t)(b * 128 + bx) * 37056 + 36864 + t] = s;
    else if (mode == 1)
      atomicAdd(part + (size_t)(b * 64 + (bx >> 1)) * 37056 + 36864 + t, s);
    else
      atomicAdd(S + b * 192 + t, s);
  }
}

// ---------------- K1.5: deterministic reduce of P partials/batch ----------------
__global__ void k1r_reduce(const float* __restrict__ part, float* __restrict__ G,
                           float* __restrict__ S, int P) {
  int idx = blockIdx.x * 256 + threadIdx.x;
  if (idx >= 4 * 37056) return;
  int b = idx / 37056;
  int flat = idx % 37056;
  const float* base = part + (size_t)b * P * 37056 + flat;
  float v0 = 0.f, v1 = 0.f, v2 = 0.f, v3 = 0.f;
  for (int q = 0; q < P; q += 4) {
    v0 += base[(size_t)(q + 0) * 37056];
    v1 += base[(size_t)(q + 1) * 37056];
    v2 += base[(size_t)(q + 2) * 37056];
    v3 += base[(size_t)(q + 3) * 37056];
  }
  float v = (v0 + v1) + (v2 + v3);
  if (flat < 36864) {
    int tt = flat >> 8;
    int I = tt / 12, J = tt % 12;
    int r = flat & 255;
    int lane = r >> 2, rg = r & 3;
    int row = I * 16 + ((lane >> 4) << 2) + rg;
    int col = J * 16 + (lane & 15);
    G[b * 36864 + row * 192 + col] = v;
  } else {
    S[b * 192 + (flat - 36864)] = v;
  }
}

// ---------------- K2: energy -> softmax -> M(fp16 swizzled), c0 ----------------
__global__ __launch_bounds__(256) void k2_small(
    const float* __restrict__ G, const float* __restrict__ S,
    const float* __restrict__ Wq, const float* __restrict__ bq,
    const float* __restrict__ Wk, const float* __restrict__ bk,
    const float* __restrict__ Wv, const float* __restrict__ bv,
    _Float16* __restrict__ Mh, float* __restrict__ c0w) {
  const int b = blockIdx.y;
  const int cbase = blockIdx.x * 8;
  const int t = threadIdx.x;
  __shared__ float T1[192 * 9];
  __shared__ float el[64 * 8];
  __shared__ float sq[8];
  __shared__ float sk[64];
  const float* Gb = G + b * 36864;
  const float* Sb = S + b * 192;

  if (t < 8) {
    float a = 0.f;
    const float* wq = Wq + (cbase + t) * 192;
    for (int i = 0; i < 192; ++i) a = fmaf(wq[i], Sb[i], a);
    sq[t] = a;
  } else if (t < 72) {
    int d = t - 8;
    float a = 0.f;
    const float* wk = Wk + d * 192;
    for (int j = 0; j < 192; ++j) a = fmaf(wk[j], Sb[j], a);
    sk[d] = a;
  }
  for (int e = t; e < 1536; e += 256) {
    int j = e % 192, cp = e / 192;
    const float* wq = Wq + (cbase + cp) * 192;
    float a = 0.f;
    for (int i = 0; i < 192; ++i) a = fmaf(wq[i], Gb[i * 192 + j], a);
    T1[j * 9 + cp] = a;
  }
  __syncthreads();
  for (int e = t; e < 512; e += 256) {
    int cp = e & 7, d = e >> 3;
    const float* wk = Wk + d * 192;
    float a = 0.f;
    for (int j = 0; j < 192; ++j) a = fmaf(T1[j * 9 + cp], wk[j], a);
    float bqc = bq[cbase + cp], bkd = bk[d];
    a += bqc * sk[d] + bkd * sq[cp] + 65536.0f * bqc * bkd;
    el[d * 8 + cp] = a * 0.125f;
  }
  __syncthreads();
  if (t < 8) {
    float mx = -3.0e38f;
    for (int d = 0; d < 64; ++d) mx = fmaxf(mx, el[d * 8 + t]);
    float sum = 0.f;
    for (int d = 0; d < 64; ++d) {
      float pv = expf(el[d * 8 + t] - mx);
      el[d * 8 + t] = pv;
      sum += pv;
    }
    float inv = 1.0f / sum;
    for (int d = 0; d < 64; ++d) el[d * 8 + t] *= inv;
  }
  __syncthreads();
  // M rows in fp16, swizzled exactly as K3's lds_m image: idx = c*192 + (i ^ ((c&7)<<3))
  for (int e = t; e < 1536; e += 256) {
    int i = e % 192, cp = e / 192;
    int c = cbase + cp;
    float a = 0.f;
    for (int d = 0; d < 64; ++d) a = fmaf(el[d * 8 + cp], Wv[d * 192 + i], a);
    Mh[(size_t)b * 12288 + c * 192 + (i ^ ((c & 7) << 3))] = (_Float16)a;
  }
  if (t < 8) {
    float a = 0.f;
    for (int d = 0; d < 64; ++d) a = fmaf(el[d * 8 + t], bv[d], a);
    c0w[b * 64 + cbase + t] = a;
  }
}

// ---------------- K3: out = M X + c0 (fp16 MFMA) ----------------
// grid (256, 4), block 256 (4 waves). Block: C[64 x 256n]; wave w: n-span w*64.
// X chunk [32 i][256 n] staged transposed into lds_x[n][32] fp16, swizzle i^=(n&3)<<3.
// M staged once (linear copy of pre-swizzled fp16 image). acc[4][4] = 64 VGPR.
__global__ __launch_bounds__(256, 3) void k3_out(
    const float* __restrict__ rgb, const float* __restrict__ hsv, const float* __restrict__ lab,
    const _Float16* __restrict__ Mh, const float* __restrict__ c0w, float* __restrict__ out) {
  __shared__ alignas(16) _Float16 lds_m[12288];
  __shared__ alignas(16) _Float16 lds_x[8192];
  __shared__ float c0l[64];
  const int t = threadIdx.x;
  const int lane = t & 63;
  const int w = t >> 6;
  const int b = blockIdx.y;
  const int nblk = blockIdx.x * 256;

  {  // stage M (24576 B) as 16B copies + c0
    const float4* msrc = (const float4*)(Mh + (size_t)b * 12288);
    float4* mdst = (float4*)lds_m;
#pragma unroll
    for (int k = 0; k < 6; ++k) mdst[t + 256 * k] = msrc[t + 256 * k];
    if (t < 64) c0l[t] = c0w[b * 64 + t];
  }

  const int xi = t & 31;   // i within chunk
  const int ng = t >> 5;   // 0..7: n-group of 32
  const float* srcs[3] = {rgb, hsv, lab};

  f32x4_t acc[4][4];
  const f32x4_t zero4 = {0.0f, 0.0f, 0.0f, 0.0f};
#pragma unroll
  for (int i = 0; i < 4; ++i)
#pragma unroll
    for (int j = 0; j < 4; ++j) acc[i][j] = zero4;

  float4 xr[8];
  auto xload = [&](int kc) {
    int ig = kc * 32 + xi;
    const float* p = srcs[ig >> 6] + (size_t)(b * 64 + (ig & 63)) * NPIX + nblk + ng * 32;
#pragma unroll
    for (int f = 0; f < 8; ++f) xr[f] = *(const float4*)(p + f * 4);
  };
  auto xwrite = [&]() {
#pragma unroll
    for (int f = 0; f < 8; ++f) {
      int n = ng * 32 + f * 4;
      lds_x[(n + 0) * 32 + (xi ^ 0)]  = (_Float16)xr[f].x;
      lds_x[(n + 1) * 32 + (xi ^ 8)]  = (_Float16)xr[f].y;
      lds_x[(n + 2) * 32 + (xi ^ 16)] = (_Float16)xr[f].z;
      lds_x[(n + 3) * 32 + (xi ^ 24)] = (_Float16)xr[f].w;
    }
  };

  const int g = lane >> 4;     // 0..3
  const int l15 = lane & 15;

  xload(0);
  for (int kc = 0; kc < 6; ++kc) {
    xwrite();
    __syncthreads();
    if (kc + 1 < 6) xload(kc + 1);
    half8_t fx[4], fm[4];
#pragma unroll
    for (int nt = 0; nt < 4; ++nt) {
      int n = w * 64 + nt * 16 + l15;
      fx[nt] = *(const half8_t*)(lds_x + n * 32 + ((8 * g) ^ ((n & 3) << 3)));
    }
#pragma unroll
    for (int ct = 0; ct < 4; ++ct) {
      int c = ct * 16 + l15;
      fm[ct] = *(const half8_t*)(lds_m + c * 192 + ((kc * 32 + 8 * g) ^ ((c & 7) << 3)));
    }
#pragma unroll
    for (int nt = 0; nt < 4; ++nt)
#pragma unroll
      for (int ct = 0; ct < 4; ++ct)
        acc[nt][ct] = __builtin_amdgcn_mfma_f32_16x16x32_f16(fx[nt], fm[ct], acc[nt][ct], 0, 0, 0);
    __syncthreads();
  }

  // epilogue: C-row (n) = 4*g + r from first operand, C-col (c) = l15 from second
#pragma unroll
  for (int ct = 0; ct < 4; ++ct) {
    int c = ct * 16 + l15;
    float c0v = c0l[c];
#pragma unroll
    for (int nt = 0; nt < 4; ++nt) {
      int n = nblk + w * 64 + nt * 16 + 4 * g;
      float4 o;
      o.x = acc[nt][ct][0] + c0v;
      o.y = acc[nt][ct][1] + c0v;
      o.z = acc[nt][ct][2] + c0v;
      o.w = acc[nt][ct][3] + c0v;
      *(float4*)(out + (size_t)(b * 64 + c) * NPIX + n) = o;
    }
  }
}

extern "C" void kernel_launch(void* const* d_in, const int* in_sizes, int n_in,
                              void* d_out, int out_size, void* d_ws, size_t ws_size,
                              hipStream_t stream) {
  const float* rgb = (const float*)d_in[0];
  const float* hsv = (const float*)d_in[1];
  const float* lab = (const float*)d_in[2];
  const float* Wq = (const float*)d_in[3];
  const float* bq = (const float*)d_in[4];
  const float* Wk = (const float*)d_in[5];
  const float* bk = (const float*)d_in[6];
  const float* Wv = (const float*)d_in[7];
  const float* bv = (const float*)d_in[8];
  float* out = (float*)d_out;
  float* ws = (float*)d_ws;

  float* G = ws;                            // 147456 f32
  float* S = ws + 147456;                   // 768
  _Float16* Mh = (_Float16*)(ws + 148224);  // 49152 halves = 24576 f32 slots
  float* c0w = ws + 172800;                 // 256
  float* part = ws + 173056;                // up to 512*37056 f32
  const size_t need2 = (size_t)(173056 + 512 * 37056) * 4;  // 76.6 MB
  const size_t need1 = (size_t)(173056 + 256 * 37056) * 4;  // 38.6 MB
  const int mode = ws_size >= need2 ? 2 : (ws_size >= need1 ? 1 : 0);

  if (mode == 1)
    k0_zero<<<dim3(37056), dim3(256), 0, stream>>>(part, 256 * 37056);
  else if (mode == 0)
    k0_zero<<<dim3(579), dim3(256), 0, stream>>>(ws, 148224);  // zero G + S

  k1_gram<<<dim3(128, 4), dim3(768), 0, stream>>>(rgb, hsv, lab, G, S, part, mode);
  if (mode)
    k1r_reduce<<<dim3(579), dim3(256), 0, stream>>>(part, G, S, mode == 2 ? 128 : 64);
  k2_small<<<dim3(8, 4), dim3(256), 0, stream>>>(G, S, Wq, bq, Wk, bk, Wv, bv, Mh, c0w);
  k3_out<<<dim3(256, 4), dim3(256), 0, stream>>>(rgb, hsv, lab, Mh, c0w, out);
}